// Round 14
// baseline (496.925 us; speedup 1.0000x reference)
//
#include <hip/hip_runtime.h>
#include <hip/hip_bf16.h>

// MPNN on MI355X — fused 16-node-tile msg kernel + MFMA GRU, fully pre-sorted streams.
// msg[e,o] = sum_k t[e,k]*Q[src,k,o] + q0[src,o],  Q[n] = h[n] @ W2ext
// k_msgF16 (non-persistent, 1 tile/block): MFMA Q into LDS in TRANSPOSED layout
// [row][kchunk][o][k8] (RSTR=1064 -> conflict-free b128 edge reads), then a
// barrier-free edge stream; each lane accumulates outputs o in {l8,l8+8,l8+16,l8+24}.
// Edge encoder algebraically folded. k_gruAgg4: split-bf16 MFMA GRU. No global atomics.

#define NN 100000
#define NE 320000
#define QC 1056
#define NTS 6250      // NN/16 src tiles
#define NT_D 3125     // NN/32 dst tiles
#define HB 256        // bucketing blocks
#define EPB (NE / HB) // 1250
#define RSTR 1064     // sQ row stride (shorts): 1024 data + 32 bias + 8 pad

typedef short bf16x8 __attribute__((ext_vector_type(8)));
typedef float f32x4  __attribute__((ext_vector_type(4)));

__device__ __forceinline__ float bf2f(unsigned short u) {
    return __uint_as_float(((unsigned int)u) << 16);
}
__device__ __forceinline__ unsigned short f2bf(float f) {
    unsigned int x = __float_as_uint(f);
    unsigned int r = (x + 0x7fffu + ((x >> 16) & 1u)) >> 16;
    return (unsigned short)r;
}
__device__ __forceinline__ float sigm(float x) {
    return 1.f / (1.f + __expf(-x));
}

// ---- build W2ext [32][1056] (fp32, msgC fallback only)
__global__ __launch_bounds__(256) void k_w2ext(const float* __restrict__ W2,
                                               const float* __restrict__ b2,
                                               float* __restrict__ W2ext) {
    int idx = blockIdx.x * 256 + threadIdx.x;
    if (idx >= 32 * QC) return;
    int i = idx / QC, c = idx % QC;
    float v;
    if (c < 1024) { int k = c >> 5, o = c & 31; v = W2[k * 1024 + i * 32 + o]; }
    else          { v = b2[i * 32 + (c - 1024)]; }
    W2ext[idx] = v;
}

// ---- pack W2ext into bf16 B-fragment layout (66 ct blocks)
__global__ __launch_bounds__(256) void k_w2prep(const float* __restrict__ W2,
                                                const float* __restrict__ b2,
                                                unsigned short* __restrict__ W2bf) {
    int idx = blockIdx.x * 256 + threadIdx.x;
    if (idx >= 66 * 512) return;
    int ct = idx >> 9, l = (idx >> 3) & 63, j = idx & 7;
    int kk = ((j >> 2) << 4) + ((l >> 4) << 2) + (j & 3);
    int c = ct * 16 + (l & 15);
    float v;
    if (c < 1024) { int kb = c >> 5, o = c & 31; v = W2[kb * 1024 + kk * 32 + o]; }
    else          { v = b2[kk * 32 + (c - 1024)]; }
    W2bf[idx] = f2bf(v);
}

// ---- pack combined GRU weights into B-frag bf16 hi/lo
__global__ __launch_bounds__(256) void k_wgru(const float* __restrict__ Wi,
                                              const float* __restrict__ Wh,
                                              unsigned short* __restrict__ Whi,
                                              unsigned short* __restrict__ Wlo) {
    int idx = blockIdx.x * 256 + threadIdx.x;
    if (idx >= 6144) return;
    int j = idx & 7, l = (idx >> 3) & 63, kt = (idx >> 9) & 1, nt = idx >> 10;
    int k = ((j >> 2) << 4) + ((l >> 4) << 2) + (j & 3);
    int col = nt * 16 + (l & 15);
    float v = kt ? Wh[k * 96 + col] : Wi[k * 96 + col];
    unsigned short hi = f2bf(v);
    Whi[idx] = hi;
    Wlo[idx] = f2bf(v - bf2f(hi));
}

// ---- fold edge encoder
__global__ __launch_bounds__(544) void k_wcomb(const float* __restrict__ eencW,
                                               const float* __restrict__ eencB,
                                               const float* __restrict__ enW1,
                                               const float* __restrict__ enB1,
                                               float* __restrict__ Wcomb,
                                               float* __restrict__ bcomb) {
    int tid = threadIdx.x;
    if (tid < 512) {
        int i = tid >> 5, o = tid & 31;
        float acc = 0.f;
        #pragma unroll 8
        for (int j = 0; j < 32; ++j) acc += eencW[i * 32 + j] * enW1[j * 32 + o];
        Wcomb[i * 32 + o] = acc;
    } else {
        int o = tid - 512;
        float acc = enB1[o];
        #pragma unroll 8
        for (int j = 0; j < 32; ++j) acc += eencB[j] * enW1[j * 32 + o];
        bcomb[o] = acc;
    }
}

// ---- node encoder + projection
__global__ __launch_bounds__(256) void k_node_enc(
    const int* __restrict__ nfeats, const float* __restrict__ emb,
    const float* __restrict__ encW, const float* __restrict__ encB,
    const float* __restrict__ projW, const float* __restrict__ projB,
    float* __restrict__ h) {
    __shared__ float sEncW[1024], sProjW[1024], sEncB[32], sProjB[32];
    __shared__ float sEmb[8][33], sNh[8][33];
    int tid = threadIdx.x;
    for (int i = tid; i < 1024; i += 256) { sEncW[i] = encW[i]; sProjW[i] = projW[i]; }
    if (tid < 32) { sEncB[tid] = encB[tid]; sProjB[tid] = projB[tid]; }
    int ln = tid >> 5, o = tid & 31;
    int node = blockIdx.x * 8 + ln;
    int nt = nfeats[node];
    sEmb[ln][o] = fmaxf(emb[nt * 32 + o], 0.f);
    __syncthreads();
    float acc = sEncB[o];
    #pragma unroll
    for (int i = 0; i < 32; ++i) acc += sEmb[ln][i] * sEncW[i * 32 + o];
    sNh[ln][o] = fmaxf(acc, 0.f);
    __syncthreads();
    float acc2 = sProjB[o];
    #pragma unroll
    for (int i = 0; i < 32; ++i) acc2 += sNh[ln][i] * sProjW[i * 32 + o];
    h[node * 32 + o] = fmaxf(acc2, 0.f);
}

// ---- edge encoder (folded): 128 edges/block, weights in registers, no barriers
__global__ __launch_bounds__(256) void k_edge_t3(
    const float* __restrict__ efeats, const float* __restrict__ Wcomb,
    const float* __restrict__ bcomb, const int* __restrict__ eperm,
    float* __restrict__ tS) {
    int tid = threadIdx.x;
    int el = tid >> 3, l8 = tid & 7;
    int gbase = (tid & 63) & 56;
    int c0 = l8 << 2;
    float4 w[16];
    #pragma unroll
    for (int i = 0; i < 16; ++i) w[i] = *(const float4*)(Wcomb + i * 32 + c0);
    float4 bb = *(const float4*)(bcomb + c0);
    #pragma unroll
    for (int it = 0; it < 4; ++it) {
        int p = blockIdx.x * 128 + it * 32 + el;
        int e = eperm ? eperm[p] : p;
        float2 efv = *(const float2*)(efeats + (size_t)e * 16 + (l8 << 1));
        float a0 = bb.x, a1 = bb.y, a2 = bb.z, a3 = bb.w;
        #pragma unroll
        for (int i = 0; i < 8; ++i) {
            float f0 = __shfl(efv.x, gbase + i, 64);
            float f1 = __shfl(efv.y, gbase + i, 64);
            float4 w0 = w[2 * i], w1 = w[2 * i + 1];
            a0 += f0 * w0.x + f1 * w1.x;
            a1 += f0 * w0.y + f1 * w1.y;
            a2 += f0 * w0.z + f1 * w1.z;
            a3 += f0 * w0.w + f1 * w1.w;
        }
        *(float4*)(tS + (size_t)p * 32 + c0) =
            make_float4(fmaxf(a0, 0.f), fmaxf(a1, 0.f), fmaxf(a2, 0.f), fmaxf(a3, 0.f));
    }
}

// ---- generic counting-sort bucketing
template<int NT, int SHIFT>
__global__ __launch_bounds__(256) void k_histT(const int* __restrict__ keys,
                                               int* __restrict__ blockCounts) {
    __shared__ int sHist[NT];
    int tid = threadIdx.x, b = blockIdx.x;
    for (int c = tid; c < NT; c += 256) sHist[c] = 0;
    __syncthreads();
    int beg = b * EPB, end = min(beg + EPB, NE);
    for (int e = beg + tid; e < end; e += 256)
        atomicAdd(&sHist[keys[e] >> SHIFT], 1);
    __syncthreads();
    for (int c = tid; c < NT; c += 256) blockCounts[b * NT + c] = sHist[c];
}

template<int NT>
__global__ __launch_bounds__(256) void k_colsumT(const int* __restrict__ blockCounts,
                                                 int* __restrict__ blockStart,
                                                 int* __restrict__ tileTot) {
    int c = blockIdx.x * 256 + threadIdx.x;
    if (c >= NT) return;
    int running = 0;
    #pragma unroll 8
    for (int b = 0; b < HB; ++b) {
        blockStart[b * NT + c] = running;
        running += blockCounts[b * NT + c];
    }
    tileTot[c] = running;
}

template<int NT, int SEG>
__global__ __launch_bounds__(256) void k_scanT(const int* __restrict__ tileTot,
                                               int* __restrict__ offs) {
    __shared__ int sTot[NT];
    __shared__ int sPart[257];
    int tid = threadIdx.x;
    for (int c = tid; c < NT; c += 256) sTot[c] = tileTot[c];
    __syncthreads();
    int base = tid * SEG;
    int loc = 0;
    for (int j = 0; j < SEG; ++j) {
        int c = base + j;
        if (c < NT) { int v = sTot[c]; sTot[c] = loc; loc += v; }
    }
    sPart[tid] = loc;
    __syncthreads();
    if (tid == 0) {
        int s = 0;
        for (int i = 0; i < 256; ++i) { int v = sPart[i]; sPart[i] = s; s += v; }
        sPart[256] = s;
    }
    __syncthreads();
    int add = sPart[tid];
    for (int j = 0; j < SEG; ++j) {
        int c = base + j;
        if (c < NT) sTot[c] += add;
    }
    __syncthreads();
    for (int c = tid; c < NT; c += 256) offs[c] = sTot[c];
    if (tid == 0) offs[NT] = sPart[256];
}

template<int NT, int SHIFT>
__global__ __launch_bounds__(256) void k_scatterT(const int* __restrict__ keys,
                                                  const int* __restrict__ blockStart,
                                                  const int* __restrict__ offs,
                                                  int* __restrict__ eperm) {
    __shared__ int sCur[NT];
    int tid = threadIdx.x, b = blockIdx.x;
    for (int c = tid; c < NT; c += 256)
        sCur[c] = offs[c] + blockStart[b * NT + c];
    __syncthreads();
    int beg = b * EPB, end = min(beg + EPB, NE);
    for (int e = beg + tid; e < end; e += 256) {
        int pos = atomicAdd(&sCur[keys[e] >> SHIFT], 1);
        eperm[pos] = e;
    }
}

// ---- second-level sort: within each dst tile, sort by node (32 LDS bins)
__global__ __launch_bounds__(256) void k_sortNode(
    const int* __restrict__ epermD, const int* __restrict__ dst,
    const int* __restrict__ offsD, int* __restrict__ epermD2,
    int* __restrict__ nodeOffs) {
    __shared__ int sCnt[32], sStart[32];
    int tid = threadIdx.x, d = blockIdx.x;
    int beg = offsD[d], end = offsD[d + 1];
    if (tid < 32) sCnt[tid] = 0;
    __syncthreads();
    for (int p = beg + tid; p < end; p += 256)
        atomicAdd(&sCnt[dst[epermD[p]] & 31], 1);
    __syncthreads();
    if (tid == 0) {
        int s = beg;
        for (int r = 0; r < 32; ++r) { sStart[r] = s; s += sCnt[r]; }
    }
    __syncthreads();
    if (tid < 32) {
        nodeOffs[d * 32 + tid] = sStart[tid];
        sCnt[tid] = sStart[tid];
    }
    if (d == NT_D - 1 && tid == 0) nodeOffs[NN] = end;
    __syncthreads();
    for (int p = beg + tid; p < end; p += 256) {
        int e = epermD[p];
        int pos = atomicAdd(&sCnt[dst[e] & 31], 1);
        epermD2[pos] = e;
    }
}

// ---- inverse permutation: pos[eperm[p]] = p
__global__ __launch_bounds__(256) void k_invperm(const int* __restrict__ eperm,
                                                 int* __restrict__ pos) {
    int p = blockIdx.x * 256 + threadIdx.x;
    if (p < NE) pos[eperm[p]] = p;
}

// ---- gather key into src-sorted positions
__global__ __launch_bounds__(256) void k_gatherKey(const int* __restrict__ epermS,
                                                   const int* __restrict__ key,
                                                   int* __restrict__ out) {
    int p = blockIdx.x * 256 + threadIdx.x;
    if (p < NE) out[p] = key[epermS[p]];
}

// ---- idxS[posS[epermD2[q]]] = q
__global__ __launch_bounds__(256) void k_scatterIdx(const int* __restrict__ epermD2,
                                                    const int* __restrict__ posS,
                                                    int* __restrict__ idxS) {
    int q = blockIdx.x * 256 + threadIdx.x;
    if (q < NE) idxS[posS[epermD2[q]]] = q;
}

// ---- fused per-16-node-src-tile: MFMA Q -> transposed bf16 LDS, b128 edge stream.
// MODE 0: atomicAdd into agg[idxS=dst]; MODE 1: store to msgbuf[idxS=slot].
template<int MODE>
__global__ __launch_bounds__(256) void k_msgF16(
    const float* __restrict__ h, const unsigned short* __restrict__ W2bf,
    const float* __restrict__ tS, const int* __restrict__ srcS,
    const int* __restrict__ idxS, const int* __restrict__ offs,
    float* __restrict__ outbuf) {
    __shared__ unsigned short sQ[16 * RSTR];   // 34048 B
    int tid = threadIdx.x;
    int tile = blockIdx.x;
    int beg = offs[tile], end = offs[tile + 1];
    if (beg >= end) return;
    int nodeBase = tile * 16;
    int wave = tid >> 6, lane = tid & 63;

    // A-fragment from h
    int arow = lane & 15;
    const float* hp = h + (size_t)(nodeBase + arow) * 32 + ((lane >> 4) << 2);
    float4 x0 = *(const float4*)hp;
    float4 x1 = *(const float4*)(hp + 16);
    bf16x8 a;
    a[0] = (short)f2bf(x0.x); a[1] = (short)f2bf(x0.y);
    a[2] = (short)f2bf(x0.z); a[3] = (short)f2bf(x0.w);
    a[4] = (short)f2bf(x1.x); a[5] = (short)f2bf(x1.y);
    a[6] = (short)f2bf(x1.z); a[7] = (short)f2bf(x1.w);

    f32x4 z = {0.f, 0.f, 0.f, 0.f};
    int crow0 = (lane >> 4) << 2;
    int ccol = lane & 15;
    for (int ct = wave; ct < 66; ct += 4) {
        bf16x8 b = *(const bf16x8*)(W2bf + (size_t)((ct << 6) + lane) * 8);
        f32x4 acc = __builtin_amdgcn_mfma_f32_16x16x32_bf16(a, b, z, 0, 0, 0);
        int c = (ct << 4) + ccol;
        if (c < 1024) {   // uniform per ct (ct<64)
            int k = c >> 5, o = c & 31;
            unsigned short* qp = sQ + crow0 * RSTR + ((k >> 3) << 8) + (o << 3) + (k & 7);
            qp[0 * RSTR] = f2bf(acc[0]); qp[1 * RSTR] = f2bf(acc[1]);
            qp[2 * RSTR] = f2bf(acc[2]); qp[3 * RSTR] = f2bf(acc[3]);
        } else {          // bias block (ct = 64, 65)
            unsigned short* qp = sQ + crow0 * RSTR + 1024 + (c - 1024);
            qp[0 * RSTR] = f2bf(acc[0]); qp[1 * RSTR] = f2bf(acc[1]);
            qp[2 * RSTR] = f2bf(acc[2]); qp[3 * RSTR] = f2bf(acc[3]);
        }
    }
    __syncthreads();   // the only barrier

    int el = tid >> 3, l8 = tid & 7;
    int gbase = lane & 56;
    for (int p = beg + el; p < end; p += 32) {
        int row = srcS[p] - nodeBase;      // 8 lanes same addr -> broadcast
        int widx = idxS[p];
        float4 tv = *(const float4*)(tS + (size_t)p * 32 + (l8 << 2));
        const unsigned short* qp = sQ + row * RSTR;
        // outputs o = l8 + 8i
        float a0 = bf2f(qp[1024 + l8]);
        float a1 = bf2f(qp[1024 + l8 + 8]);
        float a2 = bf2f(qp[1024 + l8 + 16]);
        float a3 = bf2f(qp[1024 + l8 + 24]);
        #pragma unroll
        for (int ch = 0; ch < 4; ++ch) {
            float t0 = __shfl(tv.x, gbase + 2 * ch, 64);
            float t1 = __shfl(tv.y, gbase + 2 * ch, 64);
            float t2 = __shfl(tv.z, gbase + 2 * ch, 64);
            float t3 = __shfl(tv.w, gbase + 2 * ch, 64);
            float t4 = __shfl(tv.x, gbase + 2 * ch + 1, 64);
            float t5 = __shfl(tv.y, gbase + 2 * ch + 1, 64);
            float t6 = __shfl(tv.z, gbase + 2 * ch + 1, 64);
            float t7 = __shfl(tv.w, gbase + 2 * ch + 1, 64);
            const unsigned short* cp = qp + (ch << 8);
            bf16x8 q0 = *(const bf16x8*)(cp + ((l8 + 0) << 3));
            bf16x8 q1 = *(const bf16x8*)(cp + ((l8 + 8) << 3));
            bf16x8 q2 = *(const bf16x8*)(cp + ((l8 + 16) << 3));
            bf16x8 q3 = *(const bf16x8*)(cp + ((l8 + 24) << 3));
            a0 += t0 * bf2f((unsigned short)q0[0]) + t1 * bf2f((unsigned short)q0[1])
                + t2 * bf2f((unsigned short)q0[2]) + t3 * bf2f((unsigned short)q0[3])
                + t4 * bf2f((unsigned short)q0[4]) + t5 * bf2f((unsigned short)q0[5])
                + t6 * bf2f((unsigned short)q0[6]) + t7 * bf2f((unsigned short)q0[7]);
            a1 += t0 * bf2f((unsigned short)q1[0]) + t1 * bf2f((unsigned short)q1[1])
                + t2 * bf2f((unsigned short)q1[2]) + t3 * bf2f((unsigned short)q1[3])
                + t4 * bf2f((unsigned short)q1[4]) + t5 * bf2f((unsigned short)q1[5])
                + t6 * bf2f((unsigned short)q1[6]) + t7 * bf2f((unsigned short)q1[7]);
            a2 += t0 * bf2f((unsigned short)q2[0]) + t1 * bf2f((unsigned short)q2[1])
                + t2 * bf2f((unsigned short)q2[2]) + t3 * bf2f((unsigned short)q2[3])
                + t4 * bf2f((unsigned short)q2[4]) + t5 * bf2f((unsigned short)q2[5])
                + t6 * bf2f((unsigned short)q2[6]) + t7 * bf2f((unsigned short)q2[7]);
            a3 += t0 * bf2f((unsigned short)q3[0]) + t1 * bf2f((unsigned short)q3[1])
                + t2 * bf2f((unsigned short)q3[2]) + t3 * bf2f((unsigned short)q3[3])
                + t4 * bf2f((unsigned short)q3[4]) + t5 * bf2f((unsigned short)q3[5])
                + t6 * bf2f((unsigned short)q3[6]) + t7 * bf2f((unsigned short)q3[7]);
        }
        if (MODE) {
            float* op = outbuf + (size_t)widx * 32;
            op[l8] = a0; op[l8 + 8] = a1; op[l8 + 16] = a2; op[l8 + 24] = a3;
        } else {
            float* op = outbuf + (size_t)widx * 32;
            atomicAdd(op + l8, a0); atomicAdd(op + l8 + 8, a1);
            atomicAdd(op + l8 + 16, a2); atomicAdd(op + l8 + 24, a3);
        }
    }
}

// ---- fallback msg (tiny ws): recompute We per edge (t in original order)
__global__ __launch_bounds__(256) void k_msgC(
    const float* __restrict__ t, const int* __restrict__ src, const int* __restrict__ dst,
    const float* __restrict__ h, const float* __restrict__ W2ext, float* __restrict__ agg) {
    __shared__ float sT[32][33], sH[32][33];
    __shared__ int sSrc[32], sDst[32];
    int tid = threadIdx.x;
    int e0 = blockIdx.x * 32;
    if (tid < 32) sSrc[tid] = src[e0 + tid];
    else if (tid < 64) sDst[tid - 32] = dst[e0 + tid - 32];
    __syncthreads();
    for (int idx = tid; idx < 1024; idx += 256) {
        int el = idx >> 5, k = idx & 31;
        sT[el][k] = t[(e0 + el) * 32 + k];
        sH[el][k] = h[(size_t)sSrc[el] * 32 + k];
    }
    __syncthreads();
    int el = tid >> 3, l8 = tid & 7;
    int c0 = l8 * 4;
    float m0 = 0.f, m1 = 0.f, m2 = 0.f, m3 = 0.f;
    for (int i = 0; i < 32; ++i) {
        const float* wrow = W2ext + i * QC;
        float4 wb = *(const float4*)(wrow + 1024 + c0);
        float w0 = wb.x, w1 = wb.y, w2 = wb.z, w3 = wb.w;
        #pragma unroll 8
        for (int k = 0; k < 32; ++k) {
            float tk = sT[el][k];
            float4 w = *(const float4*)(wrow + k * 32 + c0);
            w0 += tk * w.x; w1 += tk * w.y; w2 += tk * w.z; w3 += tk * w.w;
        }
        float hi = sH[el][i];
        m0 += hi * w0; m1 += hi * w1; m2 += hi * w2; m3 += hi * w3;
    }
    float* ap = agg + (size_t)sDst[el] * 32 + c0;
    atomicAdd(ap + 0, m0); atomicAdd(ap + 1, m1);
    atomicAdd(ap + 2, m2); atomicAdd(ap + 3, m3);
}

// ---- GRU step reading agg[] (MODE 0 / fallback)
__global__ __launch_bounds__(256) void k_gru(
    const float* __restrict__ agg, const float* __restrict__ convB,
    const float* __restrict__ Wi, const float* __restrict__ Wh,
    const float* __restrict__ bi, const float* __restrict__ bh,
    float* __restrict__ h) {
    __shared__ float sWi[3072], sWh[3072], sBi[96], sBh[96], sCb[32];
    __shared__ float sX[8][33], sH[8][33];
    int tid = threadIdx.x;
    for (int i = tid; i < 3072; i += 256) { sWi[i] = Wi[i]; sWh[i] = Wh[i]; }
    if (tid < 96) { sBi[tid] = bi[tid]; sBh[tid] = bh[tid]; }
    if (tid < 32) sCb[tid] = convB[tid];
    int ln = tid >> 5, o = tid & 31;
    for (int g = 0; g < 4; ++g) {
        int node = blockIdx.x * 32 + g * 8 + ln;
        float hv = h[node * 32 + o];
        float av = agg[node * 32 + o];
        __syncthreads();
        sX[ln][o] = fmaxf(av + sCb[o], 0.f);
        sH[ln][o] = hv;
        __syncthreads();
        float air = sBi[o], aiz = sBi[o + 32], ain = sBi[o + 64];
        float ahr = sBh[o], ahz = sBh[o + 32], ahn = sBh[o + 64];
        #pragma unroll 8
        for (int i = 0; i < 32; ++i) {
            float x = sX[ln][i], hh = sH[ln][i];
            air += x * sWi[i * 96 + o];      ahr += hh * sWh[i * 96 + o];
            aiz += x * sWi[i * 96 + o + 32]; ahz += hh * sWh[i * 96 + o + 32];
            ain += x * sWi[i * 96 + o + 64]; ahn += hh * sWh[i * 96 + o + 64];
        }
        float r = sigm(air + ahr);
        float zz = sigm(aiz + ahz);
        float ng = tanhf(ain + r * ahn);
        h[node * 32 + o] = (1.f - zz) * ng + zz * hv;
    }
}

// ---- MODE 1: per 32-node dst tile: segment-sum -> X in LDS, GRU via split-bf16 MFMA.
__global__ __launch_bounds__(256) void k_gruAgg4(
    const float* __restrict__ msgbuf, const int* __restrict__ nodeOffs,
    const float* __restrict__ convB,
    const unsigned short* __restrict__ Whi, const unsigned short* __restrict__ Wlo,
    const float* __restrict__ bi, const float* __restrict__ bh,
    float* __restrict__ h) {
    __shared__ float sAgg[32 * 33];
    int tid = threadIdx.x;
    int d = blockIdx.x;
    int base = d * 32;

    {
        int n8 = tid >> 3, l8 = tid & 7;
        int node = base + n8;
        int nb = nodeOffs[node], ne2 = nodeOffs[node + 1];
        float a0 = 0.f, a1 = 0.f, a2 = 0.f, a3 = 0.f;
        for (int p = nb; p < ne2; ++p) {
            float4 v = *(const float4*)(msgbuf + (size_t)p * 32 + (l8 << 2));
            a0 += v.x; a1 += v.y; a2 += v.z; a3 += v.w;
        }
        int c0 = l8 << 2;
        float4 cb = *(const float4*)(convB + c0);
        float* sp = sAgg + n8 * 33 + c0;
        sp[0] = fmaxf(a0 + cb.x, 0.f);
        sp[1] = fmaxf(a1 + cb.y, 0.f);
        sp[2] = fmaxf(a2 + cb.z, 0.f);
        sp[3] = fmaxf(a3 + cb.w, 0.f);
    }
    __syncthreads();

    int wave = tid >> 6, lane = tid & 63;
    int m = wave >> 1, c = wave & 1;
    int arow = lane & 15, kg = (lane >> 4) << 2;

    bf16x8 xhi, xlo, hhi, hlo;
    {
        const float* xp = sAgg + (m * 16 + arow) * 33 + kg;
        float4 v0 = *(const float4*)xp;
        float4 v1 = *(const float4*)(xp + 16);
        float xv[8] = {v0.x, v0.y, v0.z, v0.w, v1.x, v1.y, v1.z, v1.w};
        #pragma unroll
        for (int j = 0; j < 8; ++j) {
            unsigned short hi16 = f2bf(xv[j]);
            xhi[j] = (short)hi16;
            xlo[j] = (short)f2bf(xv[j] - bf2f(hi16));
        }
        const float* hp = h + (size_t)(base + m * 16 + arow) * 32 + kg;
        float4 w0 = *(const float4*)hp;
        float4 w1 = *(const float4*)(hp + 16);
        float hv8[8] = {w0.x, w0.y, w0.z, w0.w, w1.x, w1.y, w1.z, w1.w};
        #pragma unroll
        for (int j = 0; j < 8; ++j) {
            unsigned short hi16 = f2bf(hv8[j]);
            hhi[j] = (short)hi16;
            hlo[j] = (short)f2bf(hv8[j] - bf2f(hi16));
        }
    }

    int ccol = lane & 15, crow0 = (lane >> 4) << 2;
    int o = c * 16 + ccol;
    auto Bf = [&](int nt, int kt, const unsigned short* W) {
        return *(const bf16x8*)(W + (size_t)(((nt * 2 + kt) * 64 + lane) << 3));
    };
    f32x4 accR = {0.f, 0.f, 0.f, 0.f}, accZ = {0.f, 0.f, 0.f, 0.f};
    f32x4 accIN = {0.f, 0.f, 0.f, 0.f}, accHN = {0.f, 0.f, 0.f, 0.f};
    {
        int nt = c;
        bf16x8 b0h = Bf(nt, 0, Whi), b0l = Bf(nt, 0, Wlo);
        bf16x8 b1h = Bf(nt, 1, Whi), b1l = Bf(nt, 1, Wlo);
        accR = __builtin_amdgcn_mfma_f32_16x16x32_bf16(xhi, b0h, accR, 0, 0, 0);
        accR = __builtin_amdgcn_mfma_f32_16x16x32_bf16(xlo, b0h, accR, 0, 0, 0);
        accR = __builtin_amdgcn_mfma_f32_16x16x32_bf16(xhi, b0l, accR, 0, 0, 0);
        accR = __builtin_amdgcn_mfma_f32_16x16x32_bf16(hhi, b1h, accR, 0, 0, 0);
        accR = __builtin_amdgcn_mfma_f32_16x16x32_bf16(hlo, b1h, accR, 0, 0, 0);
        accR = __builtin_amdgcn_mfma_f32_16x16x32_bf16(hhi, b1l, accR, 0, 0, 0);
    }
    {
        int nt = 2 + c;
        bf16x8 b0h = Bf(nt, 0, Whi), b0l = Bf(nt, 0, Wlo);
        bf16x8 b1h = Bf(nt, 1, Whi), b1l = Bf(nt, 1, Wlo);
        accZ = __builtin_amdgcn_mfma_f32_16x16x32_bf16(xhi, b0h, accZ, 0, 0, 0);
        accZ = __builtin_amdgcn_mfma_f32_16x16x32_bf16(xlo, b0h, accZ, 0, 0, 0);
        accZ = __builtin_amdgcn_mfma_f32_16x16x32_bf16(xhi, b0l, accZ, 0, 0, 0);
        accZ = __builtin_amdgcn_mfma_f32_16x16x32_bf16(hhi, b1h, accZ, 0, 0, 0);
        accZ = __builtin_amdgcn_mfma_f32_16x16x32_bf16(hlo, b1h, accZ, 0, 0, 0);
        accZ = __builtin_amdgcn_mfma_f32_16x16x32_bf16(hhi, b1l, accZ, 0, 0, 0);
    }
    {
        int nt = 4 + c;
        bf16x8 b0h = Bf(nt, 0, Whi), b0l = Bf(nt, 0, Wlo);
        bf16x8 b1h = Bf(nt, 1, Whi), b1l = Bf(nt, 1, Wlo);
        accIN = __builtin_amdgcn_mfma_f32_16x16x32_bf16(xhi, b0h, accIN, 0, 0, 0);
        accIN = __builtin_amdgcn_mfma_f32_16x16x32_bf16(xlo, b0h, accIN, 0, 0, 0);
        accIN = __builtin_amdgcn_mfma_f32_16x16x32_bf16(xhi, b0l, accIN, 0, 0, 0);
        accHN = __builtin_amdgcn_mfma_f32_16x16x32_bf16(hhi, b1h, accHN, 0, 0, 0);
        accHN = __builtin_amdgcn_mfma_f32_16x16x32_bf16(hlo, b1h, accHN, 0, 0, 0);
        accHN = __builtin_amdgcn_mfma_f32_16x16x32_bf16(hhi, b1l, accHN, 0, 0, 0);
    }

    float bir = bi[o], biz = bi[32 + o], bin = bi[64 + o];
    float bhr = bh[o], bhz = bh[32 + o], bhn = bh[64 + o];
    float hv[4];
    #pragma unroll
    for (int j = 0; j < 4; ++j)
        hv[j] = h[(size_t)(base + m * 16 + crow0 + j) * 32 + o];
    __syncthreads();
    #pragma unroll
    for (int j = 0; j < 4; ++j) {
        float r  = sigm(accR[j] + bir + bhr);
        float zz = sigm(accZ[j] + biz + bhz);
        float ng = tanhf(accIN[j] + bin + r * (accHN[j] + bhn));
        h[(size_t)(base + m * 16 + crow0 + j) * 32 + o] = (1.f - zz) * ng + zz * hv[j];
    }
}

// ---- decoder
__global__ __launch_bounds__(256) void k_dec(
    const float* __restrict__ h,
    const float* __restrict__ W1, const float* __restrict__ b1, const float* __restrict__ a1,
    const float* __restrict__ W2, const float* __restrict__ b2, const float* __restrict__ a2,
    const float* __restrict__ W3, const float* __restrict__ b3, const float* __restrict__ a3,
    const float* __restrict__ W4, const float* __restrict__ b4,
    float* __restrict__ out) {
    __shared__ float sW1[1024], sW2[1024], sW3[1024], sW4[96];
    __shared__ float sB1[32], sB2[32], sB3[32], sB4[3];
    __shared__ float sYa[8][33], sYb[8][33];
    int tid = threadIdx.x;
    for (int i = tid; i < 1024; i += 256) { sW1[i] = W1[i]; sW2[i] = W2[i]; sW3[i] = W3[i]; }
    if (tid < 96) sW4[tid] = W4[tid];
    if (tid < 32) { sB1[tid] = b1[tid]; sB2[tid] = b2[tid]; sB3[tid] = b3[tid]; }
    if (tid < 3) sB4[tid] = b4[tid];
    float A1 = a1[0], A2 = a2[0], A3 = a3[0];
    int ln = tid >> 5, o = tid & 31;
    int node = blockIdx.x * 8 + ln;
    sYa[ln][o] = h[node * 32 + o];
    __syncthreads();
    float acc = sB1[o];
    #pragma unroll
    for (int i = 0; i < 32; ++i) acc += sYa[ln][i] * sW1[i * 32 + o];
    acc = acc >= 0.f ? acc : A1 * acc;
    sYb[ln][o] = acc;
    __syncthreads();
    acc = sB2[o];
    #pragma unroll
    for (int i = 0; i < 32; ++i) acc += sYb[ln][i] * sW2[i * 32 + o];
    acc = acc >= 0.f ? acc : A2 * acc;
    __syncthreads();
    sYa[ln][o] = acc;
    __syncthreads();
    acc = sB3[o];
    #pragma unroll
    for (int i = 0; i < 32; ++i) acc += sYa[ln][i] * sW3[i * 32 + o];
    acc = acc >= 0.f ? acc : A3 * acc;
    __syncthreads();
    sYb[ln][o] = acc;
    __syncthreads();
    if (o < 3) {
        float r = sB4[o];
        #pragma unroll
        for (int i = 0; i < 32; ++i) r += sYb[ln][i] * sW4[i * 3 + o];
        out[node * 3 + o] = r;
    }
}

extern "C" void kernel_launch(void* const* d_in, const int* in_sizes, int n_in,
                              void* d_out, int out_size, void* d_ws, size_t ws_size,
                              hipStream_t stream) {
    const int*   nfeats = (const int*)d_in[0];
    const float* efeats = (const float*)d_in[1];
    const int*   src    = (const int*)d_in[2];
    const int*   dst    = (const int*)d_in[3];
    const float* emb    = (const float*)d_in[4];
    const float* encW   = (const float*)d_in[5];
    const float* encB   = (const float*)d_in[6];
    const float* eencW  = (const float*)d_in[7];
    const float* eencB  = (const float*)d_in[8];
    const float* projW  = (const float*)d_in[9];
    const float* projB  = (const float*)d_in[10];
    const float* enW1   = (const float*)d_in[11];
    const float* enB1   = (const float*)d_in[12];
    const float* enW2   = (const float*)d_in[13];
    const float* enB2   = (const float*)d_in[14];
    const float* convB  = (const float*)d_in[15];
    const float* gruWi  = (const float*)d_in[16];
    const float* gruWh  = (const float*)d_in[17];
    const float* gruBi  = (const float*)d_in[18];
    const float* gruBh  = (const float*)d_in[19];
    const float* dW1 = (const float*)d_in[20]; const float* db1 = (const float*)d_in[21]; const float* da1 = (const float*)d_in[22];
    const float* dW2 = (const float*)d_in[23]; const float* db2 = (const float*)d_in[24]; const float* da2 = (const float*)d_in[25];
    const float* dW3 = (const float*)d_in[26]; const float* db3 = (const float*)d_in[27]; const float* da3 = (const float*)d_in[28];
    const float* dW4 = (const float*)d_in[29]; const float* db4 = (const float*)d_in[30];
    float* out = (float*)d_out;
    char* ws = (char*)d_ws;

    // bump allocator (256-B aligned)
    size_t cur = 0;
    auto alloc = [&](size_t n) { size_t p = cur; cur = (cur + n + 255) & ~(size_t)255; return p; };
    size_t o_h   = alloc((size_t)NN * 32 * 4);
    size_t o_t   = alloc((size_t)NE * 32 * 4);      // tS (or t in fallback)
    size_t o_w2e = alloc((size_t)32 * QC * 4);
    size_t afterCommon = cur;                       // fallback agg goes here
    size_t o_w2b = alloc((size_t)66 * 512 * 2);
    size_t o_epS = alloc((size_t)NE * 4);
    size_t o_ofS = alloc((size_t)(NTS + 1) * 4);
    size_t o_posS = alloc((size_t)NE * 4);
    size_t o_srcS = alloc((size_t)NE * 4);
    size_t o_idxS = alloc((size_t)NE * 4);
    size_t o_wcomb = alloc((size_t)(512 + 32) * 4);
    size_t baseEnd = cur;                           // MODE0 agg goes here
    size_t o_epD  = alloc((size_t)NE * 4);
    size_t o_ofD  = alloc((size_t)(NT_D + 1) * 4);
    size_t o_epD2 = alloc((size_t)NE * 4);
    size_t o_noff = alloc((size_t)(NN + 1) * 4);
    size_t o_whi  = alloc((size_t)6144 * 2);
    size_t o_wlo  = alloc((size_t)6144 * 2);
    size_t o_msg  = alloc((size_t)NE * 32 * 4);     // MODE1 msgbuf
    size_t need1 = cur;
    size_t need0 = baseEnd + (size_t)NN * 32 * 4;

    int mode;                                       // 1: node-sorted, 0: atomic, -1: msgC
    if (ws_size >= need1) mode = 1;
    else if (ws_size >= need0) mode = 0;
    else mode = -1;

    float* h     = (float*)(ws + o_h);
    float* tS    = (float*)(ws + o_t);
    float* W2ext = (float*)(ws + o_w2e);
    unsigned short* W2bf = (unsigned short*)(ws + o_w2b);
    int* epermS  = (int*)(ws + o_epS);
    int* offsS   = (int*)(ws + o_ofS);
    int* posS    = (int*)(ws + o_posS);
    int* srcS    = (int*)(ws + o_srcS);
    int* idxS    = (int*)(ws + o_idxS);
    float* Wcomb = (float*)(ws + o_wcomb);
    float* bcomb = Wcomb + 512;
    int* epermD  = (int*)(ws + o_epD);
    int* offsD   = (int*)(ws + o_ofD);
    int* epermD2 = (int*)(ws + o_epD2);
    int* nodeOffs = (int*)(ws + o_noff);
    unsigned short* gWhi = (unsigned short*)(ws + o_whi);
    unsigned short* gWlo = (unsigned short*)(ws + o_wlo);
    float* outbuf = (mode == 1) ? (float*)(ws + o_msg)
                  : (mode == 0) ? (float*)(ws + baseEnd)
                                : (float*)(ws + afterCommon);
    // scratch (prologue only) unions into outbuf region
    int* blockCounts = (int*)outbuf;                      // HB*NTS
    int* blockStart  = blockCounts + (size_t)HB * NTS;
    int* tileTot     = blockStart + (size_t)HB * NTS;

    k_node_enc<<<NN / 8, 256, 0, stream>>>(nfeats, emb, encW, encB, projW, projB, h);
    k_wcomb<<<1, 544, 0, stream>>>(eencW, eencB, enW1, enB1, Wcomb, bcomb);

    if (mode >= 0) {
        k_w2prep<<<(66 * 512 + 255) / 256, 256, 0, stream>>>(enW2, enB2, W2bf);
        // src bucketing (16-node tiles)
        k_histT<NTS, 4><<<HB, 256, 0, stream>>>(src, blockCounts);
        k_colsumT<NTS><<<(NTS + 255) / 256, 256, 0, stream>>>(blockCounts, blockStart, tileTot);
        k_scanT<NTS, 25><<<1, 256, 0, stream>>>(tileTot, offsS);
        k_scatterT<NTS, 4><<<HB, 256, 0, stream>>>(src, blockStart, offsS, epermS);
        k_invperm<<<(NE + 255) / 256, 256, 0, stream>>>(epermS, posS);
        k_gatherKey<<<(NE + 255) / 256, 256, 0, stream>>>(epermS, src, srcS);
        if (mode == 1) {
            k_wgru<<<(6144 + 255) / 256, 256, 0, stream>>>(gruWi, gruWh, gWhi, gWlo);
            k_histT<NT_D, 5><<<HB, 256, 0, stream>>>(dst, blockCounts);
            k_colsumT<NT_D><<<(NT_D + 255) / 256, 256, 0, stream>>>(blockCounts, blockStart, tileTot);
            k_scanT<NT_D, 13><<<1, 256, 0, stream>>>(tileTot, offsD);
            k_scatterT<NT_D, 5><<<HB, 256, 0, stream>>>(dst, blockStart, offsD, epermD);
            k_sortNode<<<NT_D, 256, 0, stream>>>(epermD, dst, offsD, epermD2, nodeOffs);
            k_scatterIdx<<<(NE + 255) / 256, 256, 0, stream>>>(epermD2, posS, idxS);
        } else {
            k_gatherKey<<<(NE + 255) / 256, 256, 0, stream>>>(epermS, dst, idxS);
        }
        k_edge_t3<<<NE / 128, 256, 0, stream>>>(efeats, Wcomb, bcomb, epermS, tS);
    } else {
        k_w2ext<<<(32 * QC + 255) / 256, 256, 0, stream>>>(enW2, enB2, W2ext);
        k_edge_t3<<<NE / 128, 256, 0, stream>>>(efeats, Wcomb, bcomb, nullptr, tS);
    }

    for (int s = 0; s < 3; ++s) {
        if (mode == 1) {
            k_msgF16<1><<<NTS, 256, 0, stream>>>(h, W2bf, tS, srcS, idxS, offsS, outbuf);
            k_gruAgg4<<<NT_D, 256, 0, stream>>>(outbuf, nodeOffs, convB,
                                                gWhi, gWlo, gruBi, gruBh, h);
        } else if (mode == 0) {
            hipMemsetAsync(outbuf, 0, (size_t)NN * 32 * 4, stream);
            k_msgF16<0><<<NTS, 256, 0, stream>>>(h, W2bf, tS, srcS, idxS, offsS, outbuf);
            k_gru<<<NN / 32, 256, 0, stream>>>(outbuf, convB, gruWi, gruWh, gruBi, gruBh, h);
        } else {
            hipMemsetAsync(outbuf, 0, (size_t)NN * 32 * 4, stream);
            k_msgC<<<NE / 32, 256, 0, stream>>>(tS, src, dst, h, W2ext, outbuf);
            k_gru<<<NN / 32, 256, 0, stream>>>(outbuf, convB, gruWi, gruWh, gruBi, gruBh, h);
        }
    }
    k_dec<<<NN / 8, 256, 0, stream>>>(h, dW1, db1, da1, dW2, db2, da2, dW3, db3, da3, dW4, db4, out);
}

// Round 15
// 450.598 us; speedup vs baseline: 1.1028x; 1.1028x over previous
//
#include <hip/hip_runtime.h>
#include <hip/hip_bf16.h>

// MPNN on MI355X — fused 16-node-tile msg kernel + MFMA GRU, fully pre-sorted streams.
// msg[e,o] = sum_k t[e,k]*Q[src,k,o] + q0[src,o],  Q[n] = h[n] @ W2ext
// k_msgF16: per 16-node src tile, MFMA Q (16x1056 bf16) into LDS (QSTRH=1068),
// then a barrier-free edge stream: each lane loads the FULL t-row itself
// (8x float4, group lanes hit the same L1 line -> broadcast; no shfl), Q read
// from LDS (33 b64/lane). Edge encoder algebraically folded. k_gruAgg4:
// split-bf16 MFMA GRU. No global atomics (MODE1).

#define NN 100000
#define NE 320000
#define QC 1056
#define NTS 6250      // NN/16 src tiles
#define NT_D 3125     // NN/32 dst tiles
#define HB 256        // bucketing blocks
#define EPB (NE / HB) // 1250
#define QSTRH 1068    // sQ row stride (shorts)

typedef short bf16x8 __attribute__((ext_vector_type(8)));
typedef float f32x4  __attribute__((ext_vector_type(4)));

__device__ __forceinline__ float bf2f(unsigned short u) {
    return __uint_as_float(((unsigned int)u) << 16);
}
__device__ __forceinline__ unsigned short f2bf(float f) {
    unsigned int x = __float_as_uint(f);
    unsigned int r = (x + 0x7fffu + ((x >> 16) & 1u)) >> 16;
    return (unsigned short)r;
}
__device__ __forceinline__ float sigm(float x) {
    return 1.f / (1.f + __expf(-x));
}

// ---- build W2ext [32][1056] (fp32, msgC fallback only)
__global__ __launch_bounds__(256) void k_w2ext(const float* __restrict__ W2,
                                               const float* __restrict__ b2,
                                               float* __restrict__ W2ext) {
    int idx = blockIdx.x * 256 + threadIdx.x;
    if (idx >= 32 * QC) return;
    int i = idx / QC, c = idx % QC;
    float v;
    if (c < 1024) { int k = c >> 5, o = c & 31; v = W2[k * 1024 + i * 32 + o]; }
    else          { v = b2[i * 32 + (c - 1024)]; }
    W2ext[idx] = v;
}

// ---- pack W2ext into bf16 B-fragment layout
__global__ __launch_bounds__(256) void k_w2prep(const float* __restrict__ W2,
                                                const float* __restrict__ b2,
                                                unsigned short* __restrict__ W2bf) {
    int idx = blockIdx.x * 256 + threadIdx.x;
    if (idx >= 66 * 512) return;
    int ct = idx >> 9, l = (idx >> 3) & 63, j = idx & 7;
    int kk = ((j >> 2) << 4) + ((l >> 4) << 2) + (j & 3);
    int c = ct * 16 + (l & 15);
    float v;
    if (c < 1024) { int kb = c >> 5, o = c & 31; v = W2[kb * 1024 + kk * 32 + o]; }
    else          { v = b2[kk * 32 + (c - 1024)]; }
    W2bf[idx] = f2bf(v);
}

// ---- pack combined GRU weights into B-frag bf16 hi/lo
__global__ __launch_bounds__(256) void k_wgru(const float* __restrict__ Wi,
                                              const float* __restrict__ Wh,
                                              unsigned short* __restrict__ Whi,
                                              unsigned short* __restrict__ Wlo) {
    int idx = blockIdx.x * 256 + threadIdx.x;
    if (idx >= 6144) return;
    int j = idx & 7, l = (idx >> 3) & 63, kt = (idx >> 9) & 1, nt = idx >> 10;
    int k = ((j >> 2) << 4) + ((l >> 4) << 2) + (j & 3);
    int col = nt * 16 + (l & 15);
    float v = kt ? Wh[k * 96 + col] : Wi[k * 96 + col];
    unsigned short hi = f2bf(v);
    Whi[idx] = hi;
    Wlo[idx] = f2bf(v - bf2f(hi));
}

// ---- fold edge encoder
__global__ __launch_bounds__(544) void k_wcomb(const float* __restrict__ eencW,
                                               const float* __restrict__ eencB,
                                               const float* __restrict__ enW1,
                                               const float* __restrict__ enB1,
                                               float* __restrict__ Wcomb,
                                               float* __restrict__ bcomb) {
    int tid = threadIdx.x;
    if (tid < 512) {
        int i = tid >> 5, o = tid & 31;
        float acc = 0.f;
        #pragma unroll 8
        for (int j = 0; j < 32; ++j) acc += eencW[i * 32 + j] * enW1[j * 32 + o];
        Wcomb[i * 32 + o] = acc;
    } else {
        int o = tid - 512;
        float acc = enB1[o];
        #pragma unroll 8
        for (int j = 0; j < 32; ++j) acc += eencB[j] * enW1[j * 32 + o];
        bcomb[o] = acc;
    }
}

// ---- node encoder + projection
__global__ __launch_bounds__(256) void k_node_enc(
    const int* __restrict__ nfeats, const float* __restrict__ emb,
    const float* __restrict__ encW, const float* __restrict__ encB,
    const float* __restrict__ projW, const float* __restrict__ projB,
    float* __restrict__ h) {
    __shared__ float sEncW[1024], sProjW[1024], sEncB[32], sProjB[32];
    __shared__ float sEmb[8][33], sNh[8][33];
    int tid = threadIdx.x;
    for (int i = tid; i < 1024; i += 256) { sEncW[i] = encW[i]; sProjW[i] = projW[i]; }
    if (tid < 32) { sEncB[tid] = encB[tid]; sProjB[tid] = projB[tid]; }
    int ln = tid >> 5, o = tid & 31;
    int node = blockIdx.x * 8 + ln;
    int nt = nfeats[node];
    sEmb[ln][o] = fmaxf(emb[nt * 32 + o], 0.f);
    __syncthreads();
    float acc = sEncB[o];
    #pragma unroll
    for (int i = 0; i < 32; ++i) acc += sEmb[ln][i] * sEncW[i * 32 + o];
    sNh[ln][o] = fmaxf(acc, 0.f);
    __syncthreads();
    float acc2 = sProjB[o];
    #pragma unroll
    for (int i = 0; i < 32; ++i) acc2 += sNh[ln][i] * sProjW[i * 32 + o];
    h[node * 32 + o] = fmaxf(acc2, 0.f);
}

// ---- edge encoder (folded): 128 edges/block, weights in registers, no barriers
__global__ __launch_bounds__(256) void k_edge_t3(
    const float* __restrict__ efeats, const float* __restrict__ Wcomb,
    const float* __restrict__ bcomb, const int* __restrict__ eperm,
    float* __restrict__ tS) {
    int tid = threadIdx.x;
    int el = tid >> 3, l8 = tid & 7;
    int gbase = (tid & 63) & 56;
    int c0 = l8 << 2;
    float4 w[16];
    #pragma unroll
    for (int i = 0; i < 16; ++i) w[i] = *(const float4*)(Wcomb + i * 32 + c0);
    float4 bb = *(const float4*)(bcomb + c0);
    #pragma unroll
    for (int it = 0; it < 4; ++it) {
        int p = blockIdx.x * 128 + it * 32 + el;
        int e = eperm ? eperm[p] : p;
        float2 efv = *(const float2*)(efeats + (size_t)e * 16 + (l8 << 1));
        float a0 = bb.x, a1 = bb.y, a2 = bb.z, a3 = bb.w;
        #pragma unroll
        for (int i = 0; i < 8; ++i) {
            float f0 = __shfl(efv.x, gbase + i, 64);
            float f1 = __shfl(efv.y, gbase + i, 64);
            float4 w0 = w[2 * i], w1 = w[2 * i + 1];
            a0 += f0 * w0.x + f1 * w1.x;
            a1 += f0 * w0.y + f1 * w1.y;
            a2 += f0 * w0.z + f1 * w1.z;
            a3 += f0 * w0.w + f1 * w1.w;
        }
        *(float4*)(tS + (size_t)p * 32 + c0) =
            make_float4(fmaxf(a0, 0.f), fmaxf(a1, 0.f), fmaxf(a2, 0.f), fmaxf(a3, 0.f));
    }
}

// ---- generic counting-sort bucketing
template<int NT, int SHIFT>
__global__ __launch_bounds__(256) void k_histT(const int* __restrict__ keys,
                                               int* __restrict__ blockCounts) {
    __shared__ int sHist[NT];
    int tid = threadIdx.x, b = blockIdx.x;
    for (int c = tid; c < NT; c += 256) sHist[c] = 0;
    __syncthreads();
    int beg = b * EPB, end = min(beg + EPB, NE);
    for (int e = beg + tid; e < end; e += 256)
        atomicAdd(&sHist[keys[e] >> SHIFT], 1);
    __syncthreads();
    for (int c = tid; c < NT; c += 256) blockCounts[b * NT + c] = sHist[c];
}

template<int NT>
__global__ __launch_bounds__(256) void k_colsumT(const int* __restrict__ blockCounts,
                                                 int* __restrict__ blockStart,
                                                 int* __restrict__ tileTot) {
    int c = blockIdx.x * 256 + threadIdx.x;
    if (c >= NT) return;
    int running = 0;
    #pragma unroll 8
    for (int b = 0; b < HB; ++b) {
        blockStart[b * NT + c] = running;
        running += blockCounts[b * NT + c];
    }
    tileTot[c] = running;
}

template<int NT, int SEG>
__global__ __launch_bounds__(256) void k_scanT(const int* __restrict__ tileTot,
                                               int* __restrict__ offs) {
    __shared__ int sTot[NT];
    __shared__ int sPart[257];
    int tid = threadIdx.x;
    for (int c = tid; c < NT; c += 256) sTot[c] = tileTot[c];
    __syncthreads();
    int base = tid * SEG;
    int loc = 0;
    for (int j = 0; j < SEG; ++j) {
        int c = base + j;
        if (c < NT) { int v = sTot[c]; sTot[c] = loc; loc += v; }
    }
    sPart[tid] = loc;
    __syncthreads();
    if (tid == 0) {
        int s = 0;
        for (int i = 0; i < 256; ++i) { int v = sPart[i]; sPart[i] = s; s += v; }
        sPart[256] = s;
    }
    __syncthreads();
    int add = sPart[tid];
    for (int j = 0; j < SEG; ++j) {
        int c = base + j;
        if (c < NT) sTot[c] += add;
    }
    __syncthreads();
    for (int c = tid; c < NT; c += 256) offs[c] = sTot[c];
    if (tid == 0) offs[NT] = sPart[256];
}

template<int NT, int SHIFT>
__global__ __launch_bounds__(256) void k_scatterT(const int* __restrict__ keys,
                                                  const int* __restrict__ blockStart,
                                                  const int* __restrict__ offs,
                                                  int* __restrict__ eperm) {
    __shared__ int sCur[NT];
    int tid = threadIdx.x, b = blockIdx.x;
    for (int c = tid; c < NT; c += 256)
        sCur[c] = offs[c] + blockStart[b * NT + c];
    __syncthreads();
    int beg = b * EPB, end = min(beg + EPB, NE);
    for (int e = beg + tid; e < end; e += 256) {
        int pos = atomicAdd(&sCur[keys[e] >> SHIFT], 1);
        eperm[pos] = e;
    }
}

// ---- second-level sort: within each dst tile, sort by node (32 LDS bins)
__global__ __launch_bounds__(256) void k_sortNode(
    const int* __restrict__ epermD, const int* __restrict__ dst,
    const int* __restrict__ offsD, int* __restrict__ epermD2,
    int* __restrict__ nodeOffs) {
    __shared__ int sCnt[32], sStart[32];
    int tid = threadIdx.x, d = blockIdx.x;
    int beg = offsD[d], end = offsD[d + 1];
    if (tid < 32) sCnt[tid] = 0;
    __syncthreads();
    for (int p = beg + tid; p < end; p += 256)
        atomicAdd(&sCnt[dst[epermD[p]] & 31], 1);
    __syncthreads();
    if (tid == 0) {
        int s = beg;
        for (int r = 0; r < 32; ++r) { sStart[r] = s; s += sCnt[r]; }
    }
    __syncthreads();
    if (tid < 32) {
        nodeOffs[d * 32 + tid] = sStart[tid];
        sCnt[tid] = sStart[tid];
    }
    if (d == NT_D - 1 && tid == 0) nodeOffs[NN] = end;
    __syncthreads();
    for (int p = beg + tid; p < end; p += 256) {
        int e = epermD[p];
        int pos = atomicAdd(&sCnt[dst[e] & 31], 1);
        epermD2[pos] = e;
    }
}

// ---- inverse permutation: pos[eperm[p]] = p
__global__ __launch_bounds__(256) void k_invperm(const int* __restrict__ eperm,
                                                 int* __restrict__ pos) {
    int p = blockIdx.x * 256 + threadIdx.x;
    if (p < NE) pos[eperm[p]] = p;
}

// ---- gather key into src-sorted positions
__global__ __launch_bounds__(256) void k_gatherKey(const int* __restrict__ epermS,
                                                   const int* __restrict__ key,
                                                   int* __restrict__ out) {
    int p = blockIdx.x * 256 + threadIdx.x;
    if (p < NE) out[p] = key[epermS[p]];
}

// ---- idxS[posS[epermD2[q]]] = q
__global__ __launch_bounds__(256) void k_scatterIdx(const int* __restrict__ epermD2,
                                                    const int* __restrict__ posS,
                                                    int* __restrict__ idxS) {
    int q = blockIdx.x * 256 + threadIdx.x;
    if (q < NE) idxS[posS[epermD2[q]]] = q;
}

// ---- fused per-16-node-src-tile: MFMA Q -> bf16 LDS, barrier-free edge stream.
// MODE 0: atomicAdd into agg[idxS=dst]; MODE 1: store to msgbuf[idxS=slot].
template<int MODE>
__global__ __launch_bounds__(256) void k_msgF16(
    const float* __restrict__ h, const unsigned short* __restrict__ W2bf,
    const float* __restrict__ tS, const int* __restrict__ srcS,
    const int* __restrict__ idxS, const int* __restrict__ offs,
    float* __restrict__ outbuf) {
    __shared__ unsigned short sQ[16 * QSTRH];   // 34176 B
    int tid = threadIdx.x;
    int tile = blockIdx.x;
    int beg = offs[tile], end = offs[tile + 1];
    if (beg >= end) return;
    int nodeBase = tile * 16;
    int wave = tid >> 6, lane = tid & 63;

    int arow = lane & 15;
    const float* hp = h + (size_t)(nodeBase + arow) * 32 + ((lane >> 4) << 2);
    float4 x0 = *(const float4*)hp;
    float4 x1 = *(const float4*)(hp + 16);
    bf16x8 a;
    a[0] = (short)f2bf(x0.x); a[1] = (short)f2bf(x0.y);
    a[2] = (short)f2bf(x0.z); a[3] = (short)f2bf(x0.w);
    a[4] = (short)f2bf(x1.x); a[5] = (short)f2bf(x1.y);
    a[6] = (short)f2bf(x1.z); a[7] = (short)f2bf(x1.w);

    f32x4 z = {0.f, 0.f, 0.f, 0.f};
    int crow0 = (lane >> 4) << 2;
    int ccol = lane & 15;
    for (int ct = wave; ct < 66; ct += 4) {
        bf16x8 b = *(const bf16x8*)(W2bf + (size_t)((ct << 6) + lane) * 8);
        f32x4 acc = __builtin_amdgcn_mfma_f32_16x16x32_bf16(a, b, z, 0, 0, 0);
        unsigned short* qp = sQ + crow0 * QSTRH + (ct << 4) + ccol;
        qp[0 * QSTRH] = f2bf(acc[0]); qp[1 * QSTRH] = f2bf(acc[1]);
        qp[2 * QSTRH] = f2bf(acc[2]); qp[3 * QSTRH] = f2bf(acc[3]);
    }
    __syncthreads();   // the only barrier

    int el = tid >> 3, l8 = tid & 7;
    for (int p = beg + el; p < end; p += 32) {
        int row = srcS[p] - nodeBase;      // 8 lanes same addr -> broadcast
        int widx = idxS[p];
        // load the FULL t-row (group lanes read identical addresses -> L1 broadcast)
        float4 tq[8];
        #pragma unroll
        for (int i = 0; i < 8; ++i)
            tq[i] = *(const float4*)(tS + (size_t)p * 32 + (i << 2));
        const unsigned short* qp = sQ + row * QSTRH + (l8 << 2);
        ushort4 qb = *(const ushort4*)(qp + 1024);
        float a0 = bf2f(qb.x), a1 = bf2f(qb.y), a2 = bf2f(qb.z), a3 = bf2f(qb.w);
        #pragma unroll
        for (int kk = 0; kk < 8; ++kk) {
            float t0 = tq[kk].x, t1 = tq[kk].y, t2 = tq[kk].z, t3 = tq[kk].w;
            ushort4 q0 = *(const ushort4*)(qp + ((kk << 2) + 0) * 32);
            ushort4 q1 = *(const ushort4*)(qp + ((kk << 2) + 1) * 32);
            ushort4 q2 = *(const ushort4*)(qp + ((kk << 2) + 2) * 32);
            ushort4 q3 = *(const ushort4*)(qp + ((kk << 2) + 3) * 32);
            a0 += t0 * bf2f(q0.x); a1 += t0 * bf2f(q0.y);
            a2 += t0 * bf2f(q0.z); a3 += t0 * bf2f(q0.w);
            a0 += t1 * bf2f(q1.x); a1 += t1 * bf2f(q1.y);
            a2 += t1 * bf2f(q1.z); a3 += t1 * bf2f(q1.w);
            a0 += t2 * bf2f(q2.x); a1 += t2 * bf2f(q2.y);
            a2 += t2 * bf2f(q2.z); a3 += t2 * bf2f(q2.w);
            a0 += t3 * bf2f(q3.x); a1 += t3 * bf2f(q3.y);
            a2 += t3 * bf2f(q3.z); a3 += t3 * bf2f(q3.w);
        }
        if (MODE) {
            *(float4*)(outbuf + (size_t)widx * 32 + (l8 << 2)) =
                make_float4(a0, a1, a2, a3);
        } else {
            float* ap = outbuf + (size_t)widx * 32 + (l8 << 2);
            atomicAdd(ap + 0, a0); atomicAdd(ap + 1, a1);
            atomicAdd(ap + 2, a2); atomicAdd(ap + 3, a3);
        }
    }
}

// ---- fallback msg (tiny ws): recompute We per edge (t in original order)
__global__ __launch_bounds__(256) void k_msgC(
    const float* __restrict__ t, const int* __restrict__ src, const int* __restrict__ dst,
    const float* __restrict__ h, const float* __restrict__ W2ext, float* __restrict__ agg) {
    __shared__ float sT[32][33], sH[32][33];
    __shared__ int sSrc[32], sDst[32];
    int tid = threadIdx.x;
    int e0 = blockIdx.x * 32;
    if (tid < 32) sSrc[tid] = src[e0 + tid];
    else if (tid < 64) sDst[tid - 32] = dst[e0 + tid - 32];
    __syncthreads();
    for (int idx = tid; idx < 1024; idx += 256) {
        int el = idx >> 5, k = idx & 31;
        sT[el][k] = t[(e0 + el) * 32 + k];
        sH[el][k] = h[(size_t)sSrc[el] * 32 + k];
    }
    __syncthreads();
    int el = tid >> 3, l8 = tid & 7;
    int c0 = l8 * 4;
    float m0 = 0.f, m1 = 0.f, m2 = 0.f, m3 = 0.f;
    for (int i = 0; i < 32; ++i) {
        const float* wrow = W2ext + i * QC;
        float4 wb = *(const float4*)(wrow + 1024 + c0);
        float w0 = wb.x, w1 = wb.y, w2 = wb.z, w3 = wb.w;
        #pragma unroll 8
        for (int k = 0; k < 32; ++k) {
            float tk = sT[el][k];
            float4 w = *(const float4*)(wrow + k * 32 + c0);
            w0 += tk * w.x; w1 += tk * w.y; w2 += tk * w.z; w3 += tk * w.w;
        }
        float hi = sH[el][i];
        m0 += hi * w0; m1 += hi * w1; m2 += hi * w2; m3 += hi * w3;
    }
    float* ap = agg + (size_t)sDst[el] * 32 + c0;
    atomicAdd(ap + 0, m0); atomicAdd(ap + 1, m1);
    atomicAdd(ap + 2, m2); atomicAdd(ap + 3, m3);
}

// ---- GRU step reading agg[] (MODE 0 / fallback)
__global__ __launch_bounds__(256) void k_gru(
    const float* __restrict__ agg, const float* __restrict__ convB,
    const float* __restrict__ Wi, const float* __restrict__ Wh,
    const float* __restrict__ bi, const float* __restrict__ bh,
    float* __restrict__ h) {
    __shared__ float sWi[3072], sWh[3072], sBi[96], sBh[96], sCb[32];
    __shared__ float sX[8][33], sH[8][33];
    int tid = threadIdx.x;
    for (int i = tid; i < 3072; i += 256) { sWi[i] = Wi[i]; sWh[i] = Wh[i]; }
    if (tid < 96) { sBi[tid] = bi[tid]; sBh[tid] = bh[tid]; }
    if (tid < 32) sCb[tid] = convB[tid];
    int ln = tid >> 5, o = tid & 31;
    for (int g = 0; g < 4; ++g) {
        int node = blockIdx.x * 32 + g * 8 + ln;
        float hv = h[node * 32 + o];
        float av = agg[node * 32 + o];
        __syncthreads();
        sX[ln][o] = fmaxf(av + sCb[o], 0.f);
        sH[ln][o] = hv;
        __syncthreads();
        float air = sBi[o], aiz = sBi[o + 32], ain = sBi[o + 64];
        float ahr = sBh[o], ahz = sBh[o + 32], ahn = sBh[o + 64];
        #pragma unroll 8
        for (int i = 0; i < 32; ++i) {
            float x = sX[ln][i], hh = sH[ln][i];
            air += x * sWi[i * 96 + o];      ahr += hh * sWh[i * 96 + o];
            aiz += x * sWi[i * 96 + o + 32]; ahz += hh * sWh[i * 96 + o + 32];
            ain += x * sWi[i * 96 + o + 64]; ahn += hh * sWh[i * 96 + o + 64];
        }
        float r = sigm(air + ahr);
        float zz = sigm(aiz + ahz);
        float ng = tanhf(ain + r * ahn);
        h[node * 32 + o] = (1.f - zz) * ng + zz * hv;
    }
}

// ---- MODE 1: per 32-node dst tile: segment-sum -> X in LDS, GRU via split-bf16 MFMA.
__global__ __launch_bounds__(256) void k_gruAgg4(
    const float* __restrict__ msgbuf, const int* __restrict__ nodeOffs,
    const float* __restrict__ convB,
    const unsigned short* __restrict__ Whi, const unsigned short* __restrict__ Wlo,
    const float* __restrict__ bi, const float* __restrict__ bh,
    float* __restrict__ h) {
    __shared__ float sAgg[32 * 33];
    int tid = threadIdx.x;
    int d = blockIdx.x;
    int base = d * 32;

    {
        int n8 = tid >> 3, l8 = tid & 7;
        int node = base + n8;
        int nb = nodeOffs[node], ne2 = nodeOffs[node + 1];
        float a0 = 0.f, a1 = 0.f, a2 = 0.f, a3 = 0.f;
        for (int p = nb; p < ne2; ++p) {
            float4 v = *(const float4*)(msgbuf + (size_t)p * 32 + (l8 << 2));
            a0 += v.x; a1 += v.y; a2 += v.z; a3 += v.w;
        }
        int c0 = l8 << 2;
        float4 cb = *(const float4*)(convB + c0);
        float* sp = sAgg + n8 * 33 + c0;
        sp[0] = fmaxf(a0 + cb.x, 0.f);
        sp[1] = fmaxf(a1 + cb.y, 0.f);
        sp[2] = fmaxf(a2 + cb.z, 0.f);
        sp[3] = fmaxf(a3 + cb.w, 0.f);
    }
    __syncthreads();

    int wave = tid >> 6, lane = tid & 63;
    int m = wave >> 1, c = wave & 1;
    int arow = lane & 15, kg = (lane >> 4) << 2;

    bf16x8 xhi, xlo, hhi, hlo;
    {
        const float* xp = sAgg + (m * 16 + arow) * 33 + kg;
        float4 v0 = *(const float4*)xp;
        float4 v1 = *(const float4*)(xp + 16);
        float xv[8] = {v0.x, v0.y, v0.z, v0.w, v1.x, v1.y, v1.z, v1.w};
        #pragma unroll
        for (int j = 0; j < 8; ++j) {
            unsigned short hi16 = f2bf(xv[j]);
            xhi[j] = (short)hi16;
            xlo[j] = (short)f2bf(xv[j] - bf2f(hi16));
        }
        const float* hp = h + (size_t)(base + m * 16 + arow) * 32 + kg;
        float4 w0 = *(const float4*)hp;
        float4 w1 = *(const float4*)(hp + 16);
        float hv8[8] = {w0.x, w0.y, w0.z, w0.w, w1.x, w1.y, w1.z, w1.w};
        #pragma unroll
        for (int j = 0; j < 8; ++j) {
            unsigned short hi16 = f2bf(hv8[j]);
            hhi[j] = (short)hi16;
            hlo[j] = (short)f2bf(hv8[j] - bf2f(hi16));
        }
    }

    int ccol = lane & 15, crow0 = (lane >> 4) << 2;
    int o = c * 16 + ccol;
    auto Bf = [&](int nt, int kt, const unsigned short* W) {
        return *(const bf16x8*)(W + (size_t)(((nt * 2 + kt) * 64 + lane) << 3));
    };
    f32x4 accR = {0.f, 0.f, 0.f, 0.f}, accZ = {0.f, 0.f, 0.f, 0.f};
    f32x4 accIN = {0.f, 0.f, 0.f, 0.f}, accHN = {0.f, 0.f, 0.f, 0.f};
    {
        int nt = c;
        bf16x8 b0h = Bf(nt, 0, Whi), b0l = Bf(nt, 0, Wlo);
        bf16x8 b1h = Bf(nt, 1, Whi), b1l = Bf(nt, 1, Wlo);
        accR = __builtin_amdgcn_mfma_f32_16x16x32_bf16(xhi, b0h, accR, 0, 0, 0);
        accR = __builtin_amdgcn_mfma_f32_16x16x32_bf16(xlo, b0h, accR, 0, 0, 0);
        accR = __builtin_amdgcn_mfma_f32_16x16x32_bf16(xhi, b0l, accR, 0, 0, 0);
        accR = __builtin_amdgcn_mfma_f32_16x16x32_bf16(hhi, b1h, accR, 0, 0, 0);
        accR = __builtin_amdgcn_mfma_f32_16x16x32_bf16(hlo, b1h, accR, 0, 0, 0);
        accR = __builtin_amdgcn_mfma_f32_16x16x32_bf16(hhi, b1l, accR, 0, 0, 0);
    }
    {
        int nt = 2 + c;
        bf16x8 b0h = Bf(nt, 0, Whi), b0l = Bf(nt, 0, Wlo);
        bf16x8 b1h = Bf(nt, 1, Whi), b1l = Bf(nt, 1, Wlo);
        accZ = __builtin_amdgcn_mfma_f32_16x16x32_bf16(xhi, b0h, accZ, 0, 0, 0);
        accZ = __builtin_amdgcn_mfma_f32_16x16x32_bf16(xlo, b0h, accZ, 0, 0, 0);
        accZ = __builtin_amdgcn_mfma_f32_16x16x32_bf16(xhi, b0l, accZ, 0, 0, 0);
        accZ = __builtin_amdgcn_mfma_f32_16x16x32_bf16(hhi, b1h, accZ, 0, 0, 0);
        accZ = __builtin_amdgcn_mfma_f32_16x16x32_bf16(hlo, b1h, accZ, 0, 0, 0);
        accZ = __builtin_amdgcn_mfma_f32_16x16x32_bf16(hhi, b1l, accZ, 0, 0, 0);
    }
    {
        int nt = 4 + c;
        bf16x8 b0h = Bf(nt, 0, Whi), b0l = Bf(nt, 0, Wlo);
        bf16x8 b1h = Bf(nt, 1, Whi), b1l = Bf(nt, 1, Wlo);
        accIN = __builtin_amdgcn_mfma_f32_16x16x32_bf16(xhi, b0h, accIN, 0, 0, 0);
        accIN = __builtin_amdgcn_mfma_f32_16x16x32_bf16(xlo, b0h, accIN, 0, 0, 0);
        accIN = __builtin_amdgcn_mfma_f32_16x16x32_bf16(xhi, b0l, accIN, 0, 0, 0);
        accHN = __builtin_amdgcn_mfma_f32_16x16x32_bf16(hhi, b1h, accHN, 0, 0, 0);
        accHN = __builtin_amdgcn_mfma_f32_16x16x32_bf16(hlo, b1h, accHN, 0, 0, 0);
        accHN = __builtin_amdgcn_mfma_f32_16x16x32_bf16(hhi, b1l, accHN, 0, 0, 0);
    }

    float bir = bi[o], biz = bi[32 + o], bin = bi[64 + o];
    float bhr = bh[o], bhz = bh[32 + o], bhn = bh[64 + o];
    float hv[4];
    #pragma unroll
    for (int j = 0; j < 4; ++j)
        hv[j] = h[(size_t)(base + m * 16 + crow0 + j) * 32 + o];
    __syncthreads();
    #pragma unroll
    for (int j = 0; j < 4; ++j) {
        float r  = sigm(accR[j] + bir + bhr);
        float zz = sigm(accZ[j] + biz + bhz);
        float ng = tanhf(accIN[j] + bin + r * (accHN[j] + bhn));
        h[(size_t)(base + m * 16 + crow0 + j) * 32 + o] = (1.f - zz) * ng + zz * hv[j];
    }
}

// ---- decoder
__global__ __launch_bounds__(256) void k_dec(
    const float* __restrict__ h,
    const float* __restrict__ W1, const float* __restrict__ b1, const float* __restrict__ a1,
    const float* __restrict__ W2, const float* __restrict__ b2, const float* __restrict__ a2,
    const float* __restrict__ W3, const float* __restrict__ b3, const float* __restrict__ a3,
    const float* __restrict__ W4, const float* __restrict__ b4,
    float* __restrict__ out) {
    __shared__ float sW1[1024], sW2[1024], sW3[1024], sW4[96];
    __shared__ float sB1[32], sB2[32], sB3[32], sB4[3];
    __shared__ float sYa[8][33], sYb[8][33];
    int tid = threadIdx.x;
    for (int i = tid; i < 1024; i += 256) { sW1[i] = W1[i]; sW2[i] = W2[i]; sW3[i] = W3[i]; }
    if (tid < 96) sW4[tid] = W4[tid];
    if (tid < 32) { sB1[tid] = b1[tid]; sB2[tid] = b2[tid]; sB3[tid] = b3[tid]; }
    if (tid < 3) sB4[tid] = b4[tid];
    float A1 = a1[0], A2 = a2[0], A3 = a3[0];
    int ln = tid >> 5, o = tid & 31;
    int node = blockIdx.x * 8 + ln;
    sYa[ln][o] = h[node * 32 + o];
    __syncthreads();
    float acc = sB1[o];
    #pragma unroll
    for (int i = 0; i < 32; ++i) acc += sYa[ln][i] * sW1[i * 32 + o];
    acc = acc >= 0.f ? acc : A1 * acc;
    sYb[ln][o] = acc;
    __syncthreads();
    acc = sB2[o];
    #pragma unroll
    for (int i = 0; i < 32; ++i) acc += sYb[ln][i] * sW2[i * 32 + o];
    acc = acc >= 0.f ? acc : A2 * acc;
    __syncthreads();
    sYa[ln][o] = acc;
    __syncthreads();
    acc = sB3[o];
    #pragma unroll
    for (int i = 0; i < 32; ++i) acc += sYa[ln][i] * sW3[i * 32 + o];
    acc = acc >= 0.f ? acc : A3 * acc;
    __syncthreads();
    sYb[ln][o] = acc;
    __syncthreads();
    if (o < 3) {
        float r = sB4[o];
        #pragma unroll
        for (int i = 0; i < 32; ++i) r += sYb[ln][i] * sW4[i * 3 + o];
        out[node * 3 + o] = r;
    }
}

extern "C" void kernel_launch(void* const* d_in, const int* in_sizes, int n_in,
                              void* d_out, int out_size, void* d_ws, size_t ws_size,
                              hipStream_t stream) {
    const int*   nfeats = (const int*)d_in[0];
    const float* efeats = (const float*)d_in[1];
    const int*   src    = (const int*)d_in[2];
    const int*   dst    = (const int*)d_in[3];
    const float* emb    = (const float*)d_in[4];
    const float* encW   = (const float*)d_in[5];
    const float* encB   = (const float*)d_in[6];
    const float* eencW  = (const float*)d_in[7];
    const float* eencB  = (const float*)d_in[8];
    const float* projW  = (const float*)d_in[9];
    const float* projB  = (const float*)d_in[10];
    const float* enW1   = (const float*)d_in[11];
    const float* enB1   = (const float*)d_in[12];
    const float* enW2   = (const float*)d_in[13];
    const float* enB2   = (const float*)d_in[14];
    const float* convB  = (const float*)d_in[15];
    const float* gruWi  = (const float*)d_in[16];
    const float* gruWh  = (const float*)d_in[17];
    const float* gruBi  = (const float*)d_in[18];
    const float* gruBh  = (const float*)d_in[19];
    const float* dW1 = (const float*)d_in[20]; const float* db1 = (const float*)d_in[21]; const float* da1 = (const float*)d_in[22];
    const float* dW2 = (const float*)d_in[23]; const float* db2 = (const float*)d_in[24]; const float* da2 = (const float*)d_in[25];
    const float* dW3 = (const float*)d_in[26]; const float* db3 = (const float*)d_in[27]; const float* da3 = (const float*)d_in[28];
    const float* dW4 = (const float*)d_in[29]; const float* db4 = (const float*)d_in[30];
    float* out = (float*)d_out;
    char* ws = (char*)d_ws;

    // bump allocator (256-B aligned)
    size_t cur = 0;
    auto alloc = [&](size_t n) { size_t p = cur; cur = (cur + n + 255) & ~(size_t)255; return p; };
    size_t o_h   = alloc((size_t)NN * 32 * 4);
    size_t o_t   = alloc((size_t)NE * 32 * 4);      // tS (or t in fallback)
    size_t o_w2e = alloc((size_t)32 * QC * 4);
    size_t afterCommon = cur;                       // fallback agg goes here
    size_t o_w2b = alloc((size_t)66 * 512 * 2);
    size_t o_epS = alloc((size_t)NE * 4);
    size_t o_ofS = alloc((size_t)(NTS + 1) * 4);
    size_t o_posS = alloc((size_t)NE * 4);
    size_t o_srcS = alloc((size_t)NE * 4);
    size_t o_idxS = alloc((size_t)NE * 4);
    size_t o_wcomb = alloc((size_t)(512 + 32) * 4);
    size_t baseEnd = cur;                           // MODE0 agg goes here
    size_t o_epD  = alloc((size_t)NE * 4);
    size_t o_ofD  = alloc((size_t)(NT_D + 1) * 4);
    size_t o_epD2 = alloc((size_t)NE * 4);
    size_t o_noff = alloc((size_t)(NN + 1) * 4);
    size_t o_whi  = alloc((size_t)6144 * 2);
    size_t o_wlo  = alloc((size_t)6144 * 2);
    size_t o_msg  = alloc((size_t)NE * 32 * 4);     // MODE1 msgbuf
    size_t need1 = cur;
    size_t need0 = baseEnd + (size_t)NN * 32 * 4;

    int mode;                                       // 1: node-sorted, 0: atomic, -1: msgC
    if (ws_size >= need1) mode = 1;
    else if (ws_size >= need0) mode = 0;
    else mode = -1;

    float* h     = (float*)(ws + o_h);
    float* tS    = (float*)(ws + o_t);
    float* W2ext = (float*)(ws + o_w2e);
    unsigned short* W2bf = (unsigned short*)(ws + o_w2b);
    int* epermS  = (int*)(ws + o_epS);
    int* offsS   = (int*)(ws + o_ofS);
    int* posS    = (int*)(ws + o_posS);
    int* srcS    = (int*)(ws + o_srcS);
    int* idxS    = (int*)(ws + o_idxS);
    float* Wcomb = (float*)(ws + o_wcomb);
    float* bcomb = Wcomb + 512;
    int* epermD  = (int*)(ws + o_epD);
    int* offsD   = (int*)(ws + o_ofD);
    int* epermD2 = (int*)(ws + o_epD2);
    int* nodeOffs = (int*)(ws + o_noff);
    unsigned short* gWhi = (unsigned short*)(ws + o_whi);
    unsigned short* gWlo = (unsigned short*)(ws + o_wlo);
    float* outbuf = (mode == 1) ? (float*)(ws + o_msg)
                  : (mode == 0) ? (float*)(ws + baseEnd)
                                : (float*)(ws + afterCommon);
    // scratch (prologue only) unions into outbuf region
    int* blockCounts = (int*)outbuf;
    int* blockStart  = blockCounts + (size_t)HB * NTS;
    int* tileTot     = blockStart + (size_t)HB * NTS;

    k_node_enc<<<NN / 8, 256, 0, stream>>>(nfeats, emb, encW, encB, projW, projB, h);
    k_wcomb<<<1, 544, 0, stream>>>(eencW, eencB, enW1, enB1, Wcomb, bcomb);

    if (mode >= 0) {
        k_w2prep<<<(66 * 512 + 255) / 256, 256, 0, stream>>>(enW2, enB2, W2bf);
        // src bucketing (16-node tiles)
        k_histT<NTS, 4><<<HB, 256, 0, stream>>>(src, blockCounts);
        k_colsumT<NTS><<<(NTS + 255) / 256, 256, 0, stream>>>(blockCounts, blockStart, tileTot);
        k_scanT<NTS, 25><<<1, 256, 0, stream>>>(tileTot, offsS);
        k_scatterT<NTS, 4><<<HB, 256, 0, stream>>>(src, blockStart, offsS, epermS);
        k_invperm<<<(NE + 255) / 256, 256, 0, stream>>>(epermS, posS);
        k_gatherKey<<<(NE + 255) / 256, 256, 0, stream>>>(epermS, src, srcS);
        if (mode == 1) {
            k_wgru<<<(6144 + 255) / 256, 256, 0, stream>>>(gruWi, gruWh, gWhi, gWlo);
            k_histT<NT_D, 5><<<HB, 256, 0, stream>>>(dst, blockCounts);
            k_colsumT<NT_D><<<(NT_D + 255) / 256, 256, 0, stream>>>(blockCounts, blockStart, tileTot);
            k_scanT<NT_D, 13><<<1, 256, 0, stream>>>(tileTot, offsD);
            k_scatterT<NT_D, 5><<<HB, 256, 0, stream>>>(dst, blockStart, offsD, epermD);
            k_sortNode<<<NT_D, 256, 0, stream>>>(epermD, dst, offsD, epermD2, nodeOffs);
            k_scatterIdx<<<(NE + 255) / 256, 256, 0, stream>>>(epermD2, posS, idxS);
        } else {
            k_gatherKey<<<(NE + 255) / 256, 256, 0, stream>>>(epermS, dst, idxS);
        }
        k_edge_t3<<<NE / 128, 256, 0, stream>>>(efeats, Wcomb, bcomb, epermS, tS);
    } else {
        k_w2ext<<<(32 * QC + 255) / 256, 256, 0, stream>>>(enW2, enB2, W2ext);
        k_edge_t3<<<NE / 128, 256, 0, stream>>>(efeats, Wcomb, bcomb, nullptr, tS);
    }

    for (int s = 0; s < 3; ++s) {
        if (mode == 1) {
            k_msgF16<1><<<NTS, 256, 0, stream>>>(h, W2bf, tS, srcS, idxS, offsS, outbuf);
            k_gruAgg4<<<NT_D, 256, 0, stream>>>(outbuf, nodeOffs, convB,
                                                gWhi, gWlo, gruBi, gruBh, h);
        } else if (mode == 0) {
            hipMemsetAsync(outbuf, 0, (size_t)NN * 32 * 4, stream);
            k_msgF16<0><<<NTS, 256, 0, stream>>>(h, W2bf, tS, srcS, idxS, offsS, outbuf);
            k_gru<<<NN / 32, 256, 0, stream>>>(outbuf, convB, gruWi, gruWh, gruBi, gruBh, h);
        } else {
            hipMemsetAsync(outbuf, 0, (size_t)NN * 32 * 4, stream);
            k_msgC<<<NE / 32, 256, 0, stream>>>(tS, src, dst, h, W2ext, outbuf);
            k_gru<<<NN / 32, 256, 0, stream>>>(outbuf, convB, gruWi, gruWh, gruBi, gruBh, h);
        }
    }
    k_dec<<<NN / 8, 256, 0, stream>>>(h, dW1, db1, da1, dW2, db2, da2, dW3, db3, da3, dW4, db4, out);
}